// Round 2
// baseline (636.130 us; speedup 1.0000x reference)
//
#include <hip/hip_runtime.h>
#include <cstdint>
#include <cstddef>

// ---- sizes (compile-time for this problem) ----
#define S_  1024
#define B_  8
#define D_  1024
#define H_  16
#define HD_ 64
#define DFF_ 4096
#define M_  (S_*B_)      // 8192 rows
#define QKV_N (3*D_)     // 3072

typedef float f32x4 __attribute__((ext_vector_type(4)));
typedef __bf16 bf16x8 __attribute__((ext_vector_type(8)));

#define GLDS16(gp, lp) __builtin_amdgcn_global_load_lds( \
    (__attribute__((address_space(1))) void*)(gp), \
    (__attribute__((address_space(3))) void*)(lp), 16, 0, 0)

// ---------------------------------------------------------------------------
// fp32 -> bf16 conversion, 4 elems/thread
// ---------------------------------------------------------------------------
__global__ __launch_bounds__(256)
void cvt_bf16(const float* __restrict__ in, __bf16* __restrict__ out, int n4)
{
    int i = blockIdx.x * 256 + threadIdx.x;
    if (i < n4) {
        float4 v = *(const float4*)(in + (size_t)i * 4);
        __bf16 t[4] = {(__bf16)v.x, (__bf16)v.y, (__bf16)v.z, (__bf16)v.w};
        *(uint2*)(out + (size_t)i * 4) = *(uint2*)t;
    }
}

// ---------------------------------------------------------------------------
// GEMM: C[M,N] = A[M,K] * W[N,K]^T + bias[N]   (A,W bf16; C fp32 or bf16)
// 128x128 tile, BK=32, 256 threads (4 waves, 2x2 of 64x64), m97 structure.
// ---------------------------------------------------------------------------
template<bool OUT_BF16, bool RELU>
__global__ __launch_bounds__(256)
void gemm_bt(const __bf16* __restrict__ A, const __bf16* __restrict__ W,
             const float* __restrict__ bias, void* __restrict__ Cv,
             int M, int N, int K)
{
    __shared__ __bf16 As[128 * 32];
    __shared__ __bf16 Bs[128 * 32];

    const int tid  = threadIdx.x;
    const int lane = tid & 63;
    const int wv   = tid >> 6;
    const int quad = lane >> 4;
    const int l15  = lane & 15;
    const int m0 = blockIdx.x * 128;
    const int n0 = blockIdx.y * 128;
    const int wm = (wv >> 1) * 64;   // wave row offset in tile
    const int wn = (wv & 1) * 64;    // wave col offset in tile

    f32x4 acc[4][4] = {};

    for (int k0 = 0; k0 < K; k0 += 32) {
        __syncthreads();
        #pragma unroll
        for (int j = 0; j < 2; ++j) {
            int c   = j * 256 + tid;          // 512 chunks of 16B = 8KB tile
            int row = c >> 2;
            int cc  = c & 3;
            GLDS16(A + (size_t)(m0 + row) * K + k0 + cc * 8, (char*)As + c * 16);
            GLDS16(W + (size_t)(n0 + row) * K + k0 + cc * 8, (char*)Bs + c * 16);
        }
        __syncthreads();

        bf16x8 af[4], bf[4];
        #pragma unroll
        for (int i = 0; i < 4; ++i)
            af[i] = *(const bf16x8*)(As + (wm + i * 16 + l15) * 32 + quad * 8);
        #pragma unroll
        for (int j = 0; j < 4; ++j)
            bf[j] = *(const bf16x8*)(Bs + (wn + j * 16 + l15) * 32 + quad * 8);
        #pragma unroll
        for (int i = 0; i < 4; ++i)
            #pragma unroll
            for (int j = 0; j < 4; ++j)
                acc[i][j] = __builtin_amdgcn_mfma_f32_16x16x32_bf16(af[i], bf[j], acc[i][j], 0, 0, 0);
    }

    // epilogue: C row = wm + i*16 + quad*4 + r ; col = wn + j*16 + l15
    #pragma unroll
    for (int j = 0; j < 4; ++j) {
        const int col = n0 + wn + j * 16 + l15;
        const float bv = bias[col];
        #pragma unroll
        for (int i = 0; i < 4; ++i) {
            const int rbase = m0 + wm + i * 16 + quad * 4;
            #pragma unroll
            for (int r = 0; r < 4; ++r) {
                float v = acc[i][j][r] + bv;
                if (RELU) v = fmaxf(v, 0.f);
                if (OUT_BF16)
                    ((__bf16*)Cv)[(size_t)(rbase + r) * N + col] = (__bf16)v;
                else
                    ((float*)Cv)[(size_t)(rbase + r) * N + col] = v;
            }
        }
    }
}

// ---------------------------------------------------------------------------
// Flash attention: per (q-tile of 64 rows, b, h). qkv bf16 [8192, 3072].
// out bf16 [8192, 1024]. LDS tiles padded to stride 72 (bank spread).
// ---------------------------------------------------------------------------
#define TST 72   // padded LDS row stride (elements)

__global__ __launch_bounds__(256)
void attn_flash(const __bf16* __restrict__ qkv, __bf16* __restrict__ out)
{
    __shared__ __bf16 Qs[64 * TST];
    __shared__ __bf16 Ks[64 * TST];
    __shared__ __bf16 Vt[64 * TST];
    __shared__ __bf16 Ps[64 * TST];

    const int tid  = threadIdx.x;
    const int lane = tid & 63;
    const int wv   = tid >> 6;
    const int quad = lane >> 4;
    const int l15  = lane & 15;
    const int s0 = blockIdx.x * 64;
    const int b  = blockIdx.y & (B_ - 1);
    const int h  = blockIdx.y / B_;

    // stage Q tile (rows s0..s0+63, cols h*64..+63), once.
    // 64 rows x 64 cols x 2B = 8KB = 512 chunks of 16B -> 2 chunks/thread.
    #pragma unroll
    for (int j = 0; j < 2; ++j) {
        int c = j * 256 + tid;
        int i = c >> 3, cc = c & 7;
        const __bf16* g = qkv + (size_t)((s0 + i) * B_ + b) * QKV_N + h * HD_ + cc * 8;
        *(uint4*)(Qs + i * TST + cc * 8) = *(const uint4*)g;
    }

    f32x4 oacc[4] = {};
    float m_run[4], l_run[4];
    #pragma unroll
    for (int r = 0; r < 4; ++r) { m_run[r] = -1e30f; l_run[r] = 0.f; }

    for (int t0 = 0; t0 < S_; t0 += 64) {
        __syncthreads();   // previous iter's reads of Ks/Vt done
        // stage K tile: 512 chunks of 16B, 2/thread
        #pragma unroll
        for (int j = 0; j < 2; ++j) {
            int c = j * 256 + tid;
            int i = c >> 3, cc = c & 7;
            const __bf16* g = qkv + (size_t)((t0 + i) * B_ + b) * QKV_N + D_ + h * HD_ + cc * 8;
            *(uint4*)(Ks + i * TST + cc * 8) = *(const uint4*)g;
        }
        // stage V transposed: Vt[d][t]
        #pragma unroll
        for (int j = 0; j < 2; ++j) {
            int c = j * 256 + tid;
            int i = c >> 3, d8 = (c & 7) * 8;
            const __bf16* g = qkv + (size_t)((t0 + i) * B_ + b) * QKV_N + 2 * D_ + h * HD_ + d8;
            bf16x8 v = *(const bf16x8*)g;
            #pragma unroll
            for (int u = 0; u < 8; ++u) Vt[(d8 + u) * TST + i] = v[u];
        }
        __syncthreads();

        // S tile: wave wv computes q-rows [wv*16, wv*16+16) x 64 t-cols
        f32x4 sacc[4] = {};
        #pragma unroll
        for (int kk = 0; kk < 2; ++kk) {
            bf16x8 aq = *(const bf16x8*)(Qs + (wv * 16 + l15) * TST + kk * 32 + quad * 8);
            #pragma unroll
            for (int j = 0; j < 4; ++j) {
                bf16x8 bk = *(const bf16x8*)(Ks + (j * 16 + l15) * TST + kk * 32 + quad * 8);
                sacc[j] = __builtin_amdgcn_mfma_f32_16x16x32_bf16(aq, bk, sacc[j], 0, 0, 0);
            }
        }

        // online softmax per row (row = wv*16 + quad*4 + r; the row's 64 cols
        // live in the 16 lanes of this quad x 4 j-tiles)
        #pragma unroll
        for (int r = 0; r < 4; ++r) {
            float mx = -1e30f;
            #pragma unroll
            for (int j = 0; j < 4; ++j) { sacc[j][r] *= 0.125f; mx = fmaxf(mx, sacc[j][r]); }
            for (int msk = 1; msk <= 8; msk <<= 1) mx = fmaxf(mx, __shfl_xor(mx, msk, 64));
            float mnew  = fmaxf(m_run[r], mx);
            float alpha = __expf(m_run[r] - mnew);
            float rs = 0.f;
            #pragma unroll
            for (int j = 0; j < 4; ++j) {
                float p = __expf(sacc[j][r] - mnew);
                sacc[j][r] = p;
                rs += p;
            }
            for (int msk = 1; msk <= 8; msk <<= 1) rs += __shfl_xor(rs, msk, 64);
            l_run[r] = l_run[r] * alpha + rs;
            m_run[r] = mnew;
            #pragma unroll
            for (int j = 0; j < 4; ++j) oacc[j][r] *= alpha;
            // P (C-layout) -> LDS, bf16
            #pragma unroll
            for (int j = 0; j < 4; ++j)
                Ps[(wv * 16 + quad * 4 + r) * TST + j * 16 + l15] = (__bf16)sacc[j][r];
        }

        // O += P * V   (A-frag from Ps, B-frag from Vt; same-wave LDS dep)
        #pragma unroll
        for (int kk = 0; kk < 2; ++kk) {
            bf16x8 ap = *(const bf16x8*)(Ps + (wv * 16 + l15) * TST + kk * 32 + quad * 8);
            #pragma unroll
            for (int j = 0; j < 4; ++j) {
                bf16x8 bv = *(const bf16x8*)(Vt + (j * 16 + l15) * TST + kk * 32 + quad * 8);
                oacc[j] = __builtin_amdgcn_mfma_f32_16x16x32_bf16(ap, bv, oacc[j], 0, 0, 0);
            }
        }
    }

    // epilogue: normalize by l, write bf16 to out[(s*B+b)*D + h*64 + d]
    #pragma unroll
    for (int r = 0; r < 4; ++r) {
        float inv = 1.f / l_run[r];
        int s = s0 + wv * 16 + quad * 4 + r;
        #pragma unroll
        for (int j = 0; j < 4; ++j) {
            int d = j * 16 + l15;
            out[(size_t)(s * B_ + b) * D_ + h * HD_ + d] = (__bf16)(oacc[j][r] * inv);
        }
    }
}

// ---------------------------------------------------------------------------
// LayerNorm(res = a + b) * g + beta -> yout (fp32) and optional ybf (bf16)
// one row (1024) per block of 256 threads
// ---------------------------------------------------------------------------
__global__ __launch_bounds__(256)
void ln_res(const float* __restrict__ xa, const float* __restrict__ xb,
            const float* __restrict__ g, const float* __restrict__ beta,
            float* __restrict__ yout, __bf16* __restrict__ ybf)
{
    __shared__ float red[8];
    const int row = blockIdx.x;
    const int tid = threadIdx.x;
    const size_t base = (size_t)row * D_ + tid * 4;

    float4 a = *(const float4*)(xa + base);
    float4 bq = *(const float4*)(xb + base);
    float x0 = a.x + bq.x, x1 = a.y + bq.y, x2 = a.z + bq.z, x3 = a.w + bq.w;
    float s  = x0 + x1 + x2 + x3;
    float ss = x0 * x0 + x1 * x1 + x2 * x2 + x3 * x3;
    for (int msk = 1; msk <= 32; msk <<= 1) {
        s  += __shfl_xor(s,  msk, 64);
        ss += __shfl_xor(ss, msk, 64);
    }
    const int wv = tid >> 6;
    if ((tid & 63) == 0) { red[wv] = s; red[4 + wv] = ss; }
    __syncthreads();
    s  = red[0] + red[1] + red[2] + red[3];
    ss = red[4] + red[5] + red[6] + red[7];
    float mean = s * (1.f / D_);
    float var  = ss * (1.f / D_) - mean * mean;
    float rstd = rsqrtf(var + 1e-5f);

    float4 gv = *(const float4*)(g + tid * 4);
    float4 bv = *(const float4*)(beta + tid * 4);
    float y0 = (x0 - mean) * rstd * gv.x + bv.x;
    float y1 = (x1 - mean) * rstd * gv.y + bv.y;
    float y2 = (x2 - mean) * rstd * gv.z + bv.z;
    float y3 = (x3 - mean) * rstd * gv.w + bv.w;
    *(float4*)(yout + base) = make_float4(y0, y1, y2, y3);
    if (ybf) {
        __bf16 t[4] = {(__bf16)y0, (__bf16)y1, (__bf16)y2, (__bf16)y3};
        *(uint2*)(ybf + base) = *(uint2*)t;
    }
}

// ---------------------------------------------------------------------------
extern "C" void kernel_launch(void* const* d_in, const int* in_sizes, int n_in,
                              void* d_out, int out_size, void* d_ws, size_t ws_size,
                              hipStream_t stream)
{
    const float* src       = (const float*)d_in[0];
    const float* in_proj_w = (const float*)d_in[1];
    const float* in_proj_b = (const float*)d_in[2];
    const float* out_w     = (const float*)d_in[3];
    const float* out_b     = (const float*)d_in[4];
    const float* lin1_w    = (const float*)d_in[5];
    const float* lin1_b    = (const float*)d_in[6];
    const float* lin2_w    = (const float*)d_in[7];
    const float* lin2_b    = (const float*)d_in[8];
    const float* n1_g = (const float*)d_in[9];
    const float* n1_b = (const float*)d_in[10];
    const float* n2_g = (const float*)d_in[11];
    const float* n2_b = (const float*)d_in[12];

    char* ws = (char*)d_ws;
    size_t off = 0;
    auto alloc = [&](size_t bytes) { char* p = ws + off; off += (bytes + 255) & ~(size_t)255; return p; };

    __bf16* src_bf = (__bf16*)alloc((size_t)M_ * D_ * 2);        // reused as attn_out after GEMM1
    __bf16* w1     = (__bf16*)alloc((size_t)QKV_N * D_ * 2);
    __bf16* w2     = (__bf16*)alloc((size_t)D_ * D_ * 2);
    __bf16* w3     = (__bf16*)alloc((size_t)DFF_ * D_ * 2);
    __bf16* w4     = (__bf16*)alloc((size_t)D_ * DFF_ * 2);
    char*   qkv_r  = alloc((size_t)M_ * QKV_N * 2);              // 48MB; later reused for f (32MB fp32)
    char*   h_r    = alloc((size_t)M_ * DFF_ * 2);               // 64MB; first 32MB doubles as o (fp32)
    __bf16* xbf    = (__bf16*)alloc((size_t)M_ * D_ * 2);
    float*  xf     = (float*)alloc((size_t)M_ * D_ * 4);

    __bf16* qkv    = (__bf16*)qkv_r;
    float*  f      = (float*)qkv_r;       // written by GEMM4, after qkv is dead
    float*  o      = (float*)h_r;         // written by GEMM2, dead before h is written
    __bf16* hbf    = (__bf16*)h_r;
    __bf16* attn_o = src_bf;              // src_bf dead after GEMM1

    // 1) fp32 -> bf16 conversions
    cvt_bf16<<<(M_ * D_ / 4 + 255) / 256, 256, 0, stream>>>(src, src_bf, M_ * D_ / 4);
    cvt_bf16<<<(QKV_N * D_ / 4 + 255) / 256, 256, 0, stream>>>(in_proj_w, w1, QKV_N * D_ / 4);
    cvt_bf16<<<(D_ * D_ / 4 + 255) / 256, 256, 0, stream>>>(out_w, w2, D_ * D_ / 4);
    cvt_bf16<<<(DFF_ * D_ / 4 + 255) / 256, 256, 0, stream>>>(lin1_w, w3, DFF_ * D_ / 4);
    cvt_bf16<<<(D_ * DFF_ / 4 + 255) / 256, 256, 0, stream>>>(lin2_w, w4, D_ * DFF_ / 4);

    // 2) QKV projection: qkv = src * in_proj_w^T + b   [8192, 3072] bf16
    gemm_bt<true, false><<<dim3(M_ / 128, QKV_N / 128), 256, 0, stream>>>(
        src_bf, w1, in_proj_b, qkv, M_, QKV_N, D_);

    // 3) attention -> attn_o bf16 [8192, 1024]
    attn_flash<<<dim3(S_ / 64, B_ * H_), 256, 0, stream>>>(qkv, attn_o);

    // 4) out projection: o = attn_o * out_w^T + out_b   fp32
    gemm_bt<false, false><<<dim3(M_ / 128, D_ / 128), 256, 0, stream>>>(
        attn_o, w2, out_b, o, M_, D_, D_);

    // 5) x = LN(src + o) -> xf fp32, xbf bf16
    ln_res<<<M_, 256, 0, stream>>>(src, o, n1_g, n1_b, xf, xbf);

    // 6) h = relu(x * lin1_w^T + lin1_b)  bf16 [8192, 4096]
    gemm_bt<true, true><<<dim3(M_ / 128, DFF_ / 128), 256, 0, stream>>>(
        xbf, w3, lin1_b, hbf, M_, DFF_, D_);

    // 7) f = h * lin2_w^T + lin2_b  fp32 [8192, 1024]
    gemm_bt<false, false><<<dim3(M_ / 128, D_ / 128), 256, 0, stream>>>(
        hbf, w4, lin2_b, f, M_, D_, DFF_);

    // 8) out = LN(x + f)  fp32
    ln_res<<<M_, 256, 0, stream>>>(xf, f, n2_g, n2_b, (float*)d_out, nullptr);
}

// Round 3
// 560.432 us; speedup vs baseline: 1.1351x; 1.1351x over previous
//
#include <hip/hip_runtime.h>
#include <cstdint>
#include <cstddef>

// ---- sizes (compile-time for this problem) ----
#define S_  1024
#define B_  8
#define D_  1024
#define H_  16
#define HD_ 64
#define DFF_ 4096
#define M_  (S_*B_)      // 8192 rows
#define QKV_N (3*D_)     // 3072

typedef float f32x4 __attribute__((ext_vector_type(4)));
typedef __bf16 bf16x8 __attribute__((ext_vector_type(8)));

#define GLDS16(gp, lp) __builtin_amdgcn_global_load_lds( \
    (__attribute__((address_space(1))) void*)(gp), \
    (__attribute__((address_space(3))) void*)(lp), 16, 0, 0)

// ---------------------------------------------------------------------------
// fp32 -> bf16 conversion, 4 elems/thread
// ---------------------------------------------------------------------------
__global__ __launch_bounds__(256)
void cvt_bf16(const float* __restrict__ in, __bf16* __restrict__ out, int n4)
{
    int i = blockIdx.x * 256 + threadIdx.x;
    if (i < n4) {
        float4 v = *(const float4*)(in + (size_t)i * 4);
        __bf16 t[4] = {(__bf16)v.x, (__bf16)v.y, (__bf16)v.z, (__bf16)v.w};
        *(uint2*)(out + (size_t)i * 4) = *(uint2*)t;
    }
}

// ---------------------------------------------------------------------------
// GEMM: C[M,N] = A[M,K] * W[N,K]^T + bias[N]   (A,W bf16; C fp32 or bf16)
// 128x128 tile, BK=32, 256 threads (4 waves, 2x2 of 64x64), m97 structure.
// ---------------------------------------------------------------------------
template<bool OUT_BF16, bool RELU>
__global__ __launch_bounds__(256)
void gemm_bt(const __bf16* __restrict__ A, const __bf16* __restrict__ W,
             const float* __restrict__ bias, void* __restrict__ Cv,
             int M, int N, int K)
{
    __shared__ __bf16 As[128 * 32];
    __shared__ __bf16 Bs[128 * 32];

    const int tid  = threadIdx.x;
    const int lane = tid & 63;
    const int wv   = tid >> 6;
    const int quad = lane >> 4;
    const int l15  = lane & 15;
    const int m0 = blockIdx.x * 128;
    const int n0 = blockIdx.y * 128;
    const int wm = (wv >> 1) * 64;   // wave row offset in tile
    const int wn = (wv & 1) * 64;    // wave col offset in tile

    f32x4 acc[4][4] = {};

    for (int k0 = 0; k0 < K; k0 += 32) {
        __syncthreads();
        #pragma unroll
        for (int j = 0; j < 2; ++j) {
            int c   = j * 256 + tid;          // 512 chunks of 16B = 8KB tile
            int row = c >> 2;
            int cc  = c & 3;
            GLDS16(A + (size_t)(m0 + row) * K + k0 + cc * 8, (char*)As + c * 16);
            GLDS16(W + (size_t)(n0 + row) * K + k0 + cc * 8, (char*)Bs + c * 16);
        }
        __syncthreads();

        bf16x8 af[4], bf[4];
        #pragma unroll
        for (int i = 0; i < 4; ++i)
            af[i] = *(const bf16x8*)(As + (wm + i * 16 + l15) * 32 + quad * 8);
        #pragma unroll
        for (int j = 0; j < 4; ++j)
            bf[j] = *(const bf16x8*)(Bs + (wn + j * 16 + l15) * 32 + quad * 8);
        #pragma unroll
        for (int i = 0; i < 4; ++i)
            #pragma unroll
            for (int j = 0; j < 4; ++j)
                acc[i][j] = __builtin_amdgcn_mfma_f32_16x16x32_bf16(af[i], bf[j], acc[i][j], 0, 0, 0);
    }

    // epilogue: C row = wm + i*16 + quad*4 + r ; col = wn + j*16 + l15
    #pragma unroll
    for (int j = 0; j < 4; ++j) {
        const int col = n0 + wn + j * 16 + l15;
        const float bv = bias[col];
        #pragma unroll
        for (int i = 0; i < 4; ++i) {
            const int rbase = m0 + wm + i * 16 + quad * 4;
            #pragma unroll
            for (int r = 0; r < 4; ++r) {
                float v = acc[i][j][r] + bv;
                if (RELU) v = fmaxf(v, 0.f);
                if (OUT_BF16)
                    ((__bf16*)Cv)[(size_t)(rbase + r) * N + col] = (__bf16)v;
                else
                    ((float*)Cv)[(size_t)(rbase + r) * N + col] = v;
            }
        }
    }
}

// ---------------------------------------------------------------------------
// V transpose: qkv V-part [t, (b), 2D + h*64 + d] -> vt[bh][d][t]
// one 64(t) x 64(d) tile per block; odd-stride-65 LDS pad for the transpose.
// ---------------------------------------------------------------------------
__global__ __launch_bounds__(256)
void v_transpose(const __bf16* __restrict__ qkv, __bf16* __restrict__ vt)
{
    __shared__ __bf16 T[64 * 65];
    const int tid = threadIdx.x;
    const int t0  = blockIdx.x * 64;
    const int bh  = blockIdx.y;
    const int b   = bh & (B_ - 1);
    const int h   = bh / B_;

    #pragma unroll
    for (int j = 0; j < 2; ++j) {
        int c = j * 256 + tid;
        int i = c >> 3, cc = c & 7;          // t-row i, d-chunk cc
        const __bf16* g = qkv + (size_t)((t0 + i) * B_ + b) * QKV_N + 2 * D_ + h * HD_ + cc * 8;
        bf16x8 v = *(const bf16x8*)g;
        #pragma unroll
        for (int u = 0; u < 8; ++u) T[(cc * 8 + u) * 65 + i] = v[u];
    }
    __syncthreads();
    #pragma unroll
    for (int j = 0; j < 2; ++j) {
        int c = j * 256 + tid;
        int d = c >> 3, cc = c & 7;          // d-row, t-chunk cc
        __bf16 pk[8];
        #pragma unroll
        for (int u = 0; u < 8; ++u) pk[u] = T[d * 65 + cc * 8 + u];
        *(uint4*)(vt + ((size_t)bh * HD_ + d) * S_ + t0 + cc * 8) = *(uint4*)pk;
    }
}

// ---------------------------------------------------------------------------
// Flash attention, S^T formulation. qkv bf16 [8192,3072], vt bf16 [128][64][1024].
// Each block: 64 q-rows x one (b,h). S^T = K·Q^T puts each s-row's 64 t-values
// in-lane(16) + 3 quads -> 2-shuffle softmax reduction, b64 P writes.
// ---------------------------------------------------------------------------
#define TST 72   // padded LDS row stride (elements)

__global__ __launch_bounds__(256)
void attn_flash(const __bf16* __restrict__ qkv, const __bf16* __restrict__ vt,
                __bf16* __restrict__ out)
{
    __shared__ __bf16 Qs[64 * TST];
    __shared__ __bf16 Ks[64 * TST];
    __shared__ __bf16 Vt[64 * TST];
    __shared__ __bf16 Ps[64 * TST];

    const int tid  = threadIdx.x;
    const int lane = tid & 63;
    const int wv   = tid >> 6;
    const int quad = lane >> 4;
    const int l15  = lane & 15;
    const int s0 = blockIdx.x * 64;
    const int bh = blockIdx.y;
    const int b  = bh & (B_ - 1);
    const int h  = bh / B_;

    // stage Q tile (rows s0..s0+63, cols h*64..+63): 512 x 16B chunks
    #pragma unroll
    for (int j = 0; j < 2; ++j) {
        int c = j * 256 + tid;
        int i = c >> 3, cc = c & 7;
        const __bf16* g = qkv + (size_t)((s0 + i) * B_ + b) * QKV_N + h * HD_ + cc * 8;
        *(uint4*)(Qs + i * TST + cc * 8) = *(const uint4*)g;
    }

    f32x4 oacc[4] = {};
    float m_run = -1e30f, l_run = 0.f;
    const float C2   = 0.125f * 1.44269504f;   // scale folded into exp2 arg
    const float LOG2E = 1.44269504f;

    for (int t0 = 0; t0 < S_; t0 += 64) {
        __syncthreads();   // previous iter's reads of Ks/Vt done
        // stage K tile (natural [t][d]) — clean b128 writes
        #pragma unroll
        for (int j = 0; j < 2; ++j) {
            int c = j * 256 + tid;
            int i = c >> 3, cc = c & 7;
            const __bf16* g = qkv + (size_t)((t0 + i) * B_ + b) * QKV_N + D_ + h * HD_ + cc * 8;
            *(uint4*)(Ks + i * TST + cc * 8) = *(const uint4*)g;
        }
        // stage Vt tile from pre-transposed global: rows d, cols t0..t0+63
        #pragma unroll
        for (int j = 0; j < 2; ++j) {
            int c = j * 256 + tid;
            int d = c >> 3, cc = c & 7;
            const __bf16* g = vt + ((size_t)bh * HD_ + d) * S_ + t0 + cc * 8;
            *(uint4*)(Vt + d * TST + cc * 8) = *(const uint4*)g;
        }
        __syncthreads();

        // S^T tile: mfma(K-rows, Q-rows) -> D[row=t (quad*4+r within j*16)][col=s (l15)]
        f32x4 sacc[4] = {};
        #pragma unroll
        for (int kk = 0; kk < 2; ++kk) {
            bf16x8 bq = *(const bf16x8*)(Qs + (wv * 16 + l15) * TST + kk * 32 + quad * 8);
            #pragma unroll
            for (int j = 0; j < 4; ++j) {
                bf16x8 ak = *(const bf16x8*)(Ks + (j * 16 + l15) * TST + kk * 32 + quad * 8);
                sacc[j] = __builtin_amdgcn_mfma_f32_16x16x32_bf16(ak, bq, sacc[j], 0, 0, 0);
            }
        }

        // online softmax: this lane's s-row = wv*16 + l15; its 16 values cover
        // t = j*16 + quad*4 + r; full 64-t reduction = in-lane 16 + quads (xor 16,32)
        float mx = sacc[0][0];
        #pragma unroll
        for (int j = 0; j < 4; ++j)
            #pragma unroll
            for (int r = 0; r < 4; ++r) mx = fmaxf(mx, sacc[j][r]);
        mx = fmaxf(mx, __shfl_xor(mx, 16, 64));
        mx = fmaxf(mx, __shfl_xor(mx, 32, 64));
        float mnew = fmaxf(m_run, mx * 0.125f);
        float k1 = mnew * LOG2E;
        float rs = 0.f;
        #pragma unroll
        for (int j = 0; j < 4; ++j)
            #pragma unroll
            for (int r = 0; r < 4; ++r) {
                float p = __builtin_amdgcn_exp2f(sacc[j][r] * C2 - k1);
                sacc[j][r] = p;
                rs += p;
            }
        rs += __shfl_xor(rs, 16, 64);
        rs += __shfl_xor(rs, 32, 64);
        float alpha = __builtin_amdgcn_exp2f((m_run - mnew) * LOG2E);
        l_run = l_run * alpha + rs;
        m_run = mnew;

        // P^T fragments -> Ps[s][t] (pack 4 consecutive t per b64, conflict-free)
        #pragma unroll
        for (int j = 0; j < 4; ++j) {
            __bf16 pk[4] = {(__bf16)sacc[j][0], (__bf16)sacc[j][1],
                            (__bf16)sacc[j][2], (__bf16)sacc[j][3]};
            *(uint2*)(Ps + (wv * 16 + l15) * TST + j * 16 + quad * 4) = *(uint2*)pk;
        }

        // rescale O accumulator (C-layout rows s = quad*4+r): fetch alpha per row
        #pragma unroll
        for (int r = 0; r < 4; ++r) {
            float ar = __shfl(alpha, quad * 4 + r, 64);
            #pragma unroll
            for (int jd = 0; jd < 4; ++jd) oacc[jd][r] *= ar;
        }

        // O += P·V : A = Ps rows (this wave's 16 s), B = Vt rows (d)
        #pragma unroll
        for (int kk = 0; kk < 2; ++kk) {
            bf16x8 ap = *(const bf16x8*)(Ps + (wv * 16 + l15) * TST + kk * 32 + quad * 8);
            #pragma unroll
            for (int jd = 0; jd < 4; ++jd) {
                bf16x8 bv = *(const bf16x8*)(Vt + (jd * 16 + l15) * TST + kk * 32 + quad * 8);
                oacc[jd] = __builtin_amdgcn_mfma_f32_16x16x32_bf16(ap, bv, oacc[jd], 0, 0, 0);
            }
        }
    }

    // epilogue: O row s = s0 + wv*16 + quad*4 + r, col d = jd*16 + l15
    float linv = 1.f / l_run;
    #pragma unroll
    for (int r = 0; r < 4; ++r) {
        float lr = __shfl(linv, quad * 4 + r, 64);
        int s = s0 + wv * 16 + quad * 4 + r;
        #pragma unroll
        for (int jd = 0; jd < 4; ++jd) {
            int d = jd * 16 + l15;
            out[(size_t)(s * B_ + b) * D_ + h * HD_ + d] = (__bf16)(oacc[jd][r] * lr);
        }
    }
}

// ---------------------------------------------------------------------------
// LayerNorm(res = a + b) * g + beta -> yout (fp32) and optional ybf (bf16)
// ---------------------------------------------------------------------------
__global__ __launch_bounds__(256)
void ln_res(const float* __restrict__ xa, const float* __restrict__ xb,
            const float* __restrict__ g, const float* __restrict__ beta,
            float* __restrict__ yout, __bf16* __restrict__ ybf)
{
    __shared__ float red[8];
    const int row = blockIdx.x;
    const int tid = threadIdx.x;
    const size_t base = (size_t)row * D_ + tid * 4;

    float4 a = *(const float4*)(xa + base);
    float4 bq = *(const float4*)(xb + base);
    float x0 = a.x + bq.x, x1 = a.y + bq.y, x2 = a.z + bq.z, x3 = a.w + bq.w;
    float s  = x0 + x1 + x2 + x3;
    float ss = x0 * x0 + x1 * x1 + x2 * x2 + x3 * x3;
    for (int msk = 1; msk <= 32; msk <<= 1) {
        s  += __shfl_xor(s,  msk, 64);
        ss += __shfl_xor(ss, msk, 64);
    }
    const int wv = tid >> 6;
    if ((tid & 63) == 0) { red[wv] = s; red[4 + wv] = ss; }
    __syncthreads();
    s  = red[0] + red[1] + red[2] + red[3];
    ss = red[4] + red[5] + red[6] + red[7];
    float mean = s * (1.f / D_);
    float var  = ss * (1.f / D_) - mean * mean;
    float rstd = rsqrtf(var + 1e-5f);

    float4 gv = *(const float4*)(g + tid * 4);
    float4 bv = *(const float4*)(beta + tid * 4);
    float y0 = (x0 - mean) * rstd * gv.x + bv.x;
    float y1 = (x1 - mean) * rstd * gv.y + bv.y;
    float y2 = (x2 - mean) * rstd * gv.z + bv.z;
    float y3 = (x3 - mean) * rstd * gv.w + bv.w;
    *(float4*)(yout + base) = make_float4(y0, y1, y2, y3);
    if (ybf) {
        __bf16 t[4] = {(__bf16)y0, (__bf16)y1, (__bf16)y2, (__bf16)y3};
        *(uint2*)(ybf + base) = *(uint2*)t;
    }
}

// ---------------------------------------------------------------------------
extern "C" void kernel_launch(void* const* d_in, const int* in_sizes, int n_in,
                              void* d_out, int out_size, void* d_ws, size_t ws_size,
                              hipStream_t stream)
{
    const float* src       = (const float*)d_in[0];
    const float* in_proj_w = (const float*)d_in[1];
    const float* in_proj_b = (const float*)d_in[2];
    const float* out_w     = (const float*)d_in[3];
    const float* out_b     = (const float*)d_in[4];
    const float* lin1_w    = (const float*)d_in[5];
    const float* lin1_b    = (const float*)d_in[6];
    const float* lin2_w    = (const float*)d_in[7];
    const float* lin2_b    = (const float*)d_in[8];
    const float* n1_g = (const float*)d_in[9];
    const float* n1_b = (const float*)d_in[10];
    const float* n2_g = (const float*)d_in[11];
    const float* n2_b = (const float*)d_in[12];

    char* ws = (char*)d_ws;
    size_t off = 0;
    auto alloc = [&](size_t bytes) { char* p = ws + off; off += (bytes + 255) & ~(size_t)255; return p; };

    __bf16* src_bf = (__bf16*)alloc((size_t)M_ * D_ * 2);        // reused as attn_out after GEMM1
    __bf16* w1     = (__bf16*)alloc((size_t)QKV_N * D_ * 2);
    __bf16* w2     = (__bf16*)alloc((size_t)D_ * D_ * 2);
    __bf16* w3     = (__bf16*)alloc((size_t)DFF_ * D_ * 2);
    __bf16* w4     = (__bf16*)alloc((size_t)D_ * DFF_ * 2);
    char*   qkv_r  = alloc((size_t)M_ * QKV_N * 2);              // 48MB; later reused for f (32MB fp32)
    char*   h_r    = alloc((size_t)M_ * DFF_ * 2);               // 64MB; first 32MB doubles as o (fp32)
    __bf16* xbf    = (__bf16*)alloc((size_t)M_ * D_ * 2);
    float*  xf     = (float*)alloc((size_t)M_ * D_ * 4);
    __bf16* vt     = (__bf16*)alloc((size_t)B_ * H_ * HD_ * S_ * 2);  // 16.8MB transposed V

    __bf16* qkv    = (__bf16*)qkv_r;
    float*  f      = (float*)qkv_r;       // written by GEMM4, after qkv is dead
    float*  o      = (float*)h_r;         // written by GEMM2, dead before h is written
    __bf16* hbf    = (__bf16*)h_r;
    __bf16* attn_o = src_bf;              // src_bf dead after GEMM1

    // 1) fp32 -> bf16 conversions
    cvt_bf16<<<(M_ * D_ / 4 + 255) / 256, 256, 0, stream>>>(src, src_bf, M_ * D_ / 4);
    cvt_bf16<<<(QKV_N * D_ / 4 + 255) / 256, 256, 0, stream>>>(in_proj_w, w1, QKV_N * D_ / 4);
    cvt_bf16<<<(D_ * D_ / 4 + 255) / 256, 256, 0, stream>>>(out_w, w2, D_ * D_ / 4);
    cvt_bf16<<<(DFF_ * D_ / 4 + 255) / 256, 256, 0, stream>>>(lin1_w, w3, DFF_ * D_ / 4);
    cvt_bf16<<<(D_ * DFF_ / 4 + 255) / 256, 256, 0, stream>>>(lin2_w, w4, D_ * DFF_ / 4);

    // 2) QKV projection: qkv = src * in_proj_w^T + b   [8192, 3072] bf16
    gemm_bt<true, false><<<dim3(M_ / 128, QKV_N / 128), 256, 0, stream>>>(
        src_bf, w1, in_proj_b, qkv, M_, QKV_N, D_);

    // 3) V transpose -> vt[bh][d][t]
    v_transpose<<<dim3(S_ / 64, B_ * H_), 256, 0, stream>>>(qkv, vt);

    // 4) attention -> attn_o bf16 [8192, 1024]
    attn_flash<<<dim3(S_ / 64, B_ * H_), 256, 0, stream>>>(qkv, vt, attn_o);

    // 5) out projection: o = attn_o * out_w^T + out_b   fp32
    gemm_bt<false, false><<<dim3(M_ / 128, D_ / 128), 256, 0, stream>>>(
        attn_o, w2, out_b, o, M_, D_, D_);

    // 6) x = LN(src + o) -> xf fp32, xbf bf16
    ln_res<<<M_, 256, 0, stream>>>(src, o, n1_g, n1_b, xf, xbf);

    // 7) h = relu(x * lin1_w^T + lin1_b)  bf16 [8192, 4096]
    gemm_bt<true, true><<<dim3(M_ / 128, DFF_ / 128), 256, 0, stream>>>(
        xbf, w3, lin1_b, hbf, M_, DFF_, D_);

    // 8) f = h * lin2_w^T + lin2_b  fp32 [8192, 1024]
    gemm_bt<false, false><<<dim3(M_ / 128, D_ / 128), 256, 0, stream>>>(
        hbf, w4, lin2_b, f, M_, D_, DFF_);

    // 9) out = LN(x + f)  fp32
    ln_res<<<M_, 256, 0, stream>>>(xf, f, n2_g, n2_b, (float*)d_out, nullptr);
}